// Round 15
// baseline (943.291 us; speedup 1.0000x reference)
//
#include <hip/hip_runtime.h>
#include <math.h>

#define BSZ   32768
#define DD    512
#define HH    128
#define NN    1000
#define TM    16
#define NBLK  (BSZ / TM)   // 2048
#define NT    63           // 16-wide col tiles covering 1008 >= 1000
#define SPITCH 1012        // ssim row pitch (floats)
#define IPITCH 520         // simg row pitch (floats)

typedef short  bf8 __attribute__((ext_vector_type(8)));
typedef float  f4  __attribute__((ext_vector_type(4)));

__device__ __forceinline__ unsigned short cv15_f2bf(float f) {
    unsigned u = __float_as_uint(f);
    u = u + 0x7FFF + ((u >> 16) & 1);
    return (unsigned short)(u >> 16);
}
__device__ __forceinline__ float cv15_bf2f(unsigned short h) {
    return __uint_as_float(((unsigned)h) << 16);
}

// ---------- pre-kernels: transpose + bf16 hi/lo split into workspace ----------
__global__ void cv15_prep_txt(const float* __restrict__ txt,
                              unsigned short* __restrict__ th,
                              unsigned short* __restrict__ tl)
{
    int j = blockIdx.x;                       // 0..1023 (cols, padded)
    for (int k = threadIdx.x; k < DD; k += blockDim.x) {
        float v = (j < NN) ? txt[(size_t)k * NN + j] : 0.f;
        unsigned short h = cv15_f2bf(v);
        unsigned short l = cv15_f2bf(v - cv15_bf2f(h));
        th[(size_t)j * DD + k] = h;
        tl[(size_t)j * DD + k] = l;
    }
}
__global__ void cv15_prep_w1(const float* __restrict__ w1,
                             unsigned short* __restrict__ th,
                             unsigned short* __restrict__ tl)
{
    int j = blockIdx.x;                       // 0..127
    for (int k = threadIdx.x; k < DD; k += blockDim.x) {
        float v = w1[(size_t)k * HH + j];
        unsigned short h = cv15_f2bf(v);
        unsigned short l = cv15_f2bf(v - cv15_bf2f(h));
        th[(size_t)j * DD + k] = h;
        tl[(size_t)j * DD + k] = l;
    }
}
__global__ void cv15_prep_w2(const float* __restrict__ w2,
                             unsigned short* __restrict__ th,
                             unsigned short* __restrict__ tl)
{
    int j = blockIdx.x;                       // 0..511
    for (int k = threadIdx.x; k < HH; k += blockDim.x) {
        float v = w2[(size_t)k * DD + j];
        unsigned short h = cv15_f2bf(v);
        unsigned short l = cv15_f2bf(v - cv15_bf2f(h));
        th[(size_t)j * HH + k] = h;
        tl[(size_t)j * HH + k] = l;
    }
}

// ---------- main fused kernel (split-bf16 MFMA) ----------
__global__ __launch_bounds__(512)
void cv15_main(const float* __restrict__ img,
               const float* __restrict__ b1,
               const float* __restrict__ b2,
               const unsigned short* __restrict__ txtTh,
               const unsigned short* __restrict__ txtTl,
               const unsigned short* __restrict__ w1Th,
               const unsigned short* __restrict__ w1Tl,
               const unsigned short* __restrict__ w2Th,
               const unsigned short* __restrict__ w2Tl,
               const unsigned* __restrict__ target,
               float* __restrict__ partials)
{
    __shared__ float          ssim[16 * SPITCH];     // 64.8 KB; first 8320 floats double as simg
    __shared__ unsigned short YH[16 * 512];          // A-fragments hi (16 k-tiles x 64 lanes x 8)
    __shared__ unsigned short YL[16 * 512];          // A-fragments lo
    __shared__ unsigned short hfH[4 * 512];          // h fragments hi (K=128 -> 4 k-tiles)
    __shared__ unsigned short hfL[4 * 512];
    __shared__ float          sh_[16 * 136];         // h fp32 (pitch 136)
    __shared__ float          red[512];
    __shared__ float          smax[TM], sA[TM];
    __shared__ float          srow[TM][2];
    __shared__ int            stgt[TM];
    __shared__ int            sargmax[TM];
    __shared__ int            tflag;

    const int t    = threadIdx.x;
    const int w    = t >> 6;         // wave 0..7
    const int l    = t & 63;         // lane
    const int blk  = blockIdx.x;
    const int row0 = blk * TM;
    float* simg = ssim;              // fp32 img / img_adapted, pitch IPITCH

    // targets (int64-vs-int32 probe — validated)
    if (t == 0) {
        int allz = 1, small = 1;
        #pragma unroll 1
        for (int i = 0; i < 32; ++i) {
            allz  &= (target[2 * i + 1] == 0u);
            small &= (target[2 * i] < 1000000u);
        }
        tflag = (allz && small) ? 1 : 0;
    }
    __syncthreads();
    if (t < TM) {
        int r = row0 + t;
        int tg = (int)(tflag ? target[2 * r] : target[r]);
        if (tg < 0) tg = 0;
        if (tg > NN - 1) tg = NN - 1;
        stgt[t] = tg;
    }

    // P1: stage img fp32 tile
    {
        const float4* src = (const float4*)(img + (size_t)row0 * DD);
        #pragma unroll 1
        for (int i = t; i < 2048; i += 512) {
            float4 v = src[i];
            int r = (i * 4) >> 9;
            int c = (i * 4) & 511;
            *(float4*)&simg[r * IPITCH + c] = v;
        }
    }
    __syncthreads();

    // P1b: pack img A-fragments (hi/lo), 16 k-tiles
    #pragma unroll 1
    for (int p = 0; p < 2; ++p) {
        int kt = p * 8 + w;
        int row = l & 15, kb = kt * 32 + (l >> 4) * 8;
        bf8 vh, vl;
        #pragma unroll
        for (int e = 0; e < 8; ++e) {
            float x = simg[row * IPITCH + kb + e];
            unsigned short hh = cv15_f2bf(x);
            vh[e] = (short)hh;
            vl[e] = (short)cv15_f2bf(x - cv15_bf2f(hh));
        }
        *(bf8*)&YH[kt * 512 + l * 8] = vh;
        *(bf8*)&YL[kt * 512 + l * 8] = vl;
    }
    __syncthreads();

    // P2: h = relu(img @ w1 + b1). wave w -> col-tile w (cols 16w..16w+15)
    {
        f4 acc = {0.f, 0.f, 0.f, 0.f};
        const int jj = w * 16 + (l & 15);
        const unsigned short* bh = w1Th + (size_t)jj * DD + ((l >> 4) * 8);
        const unsigned short* bl = w1Tl + (size_t)jj * DD + ((l >> 4) * 8);
        #pragma unroll 4
        for (int kt = 0; kt < 16; ++kt) {
            bf8 ah = *(const bf8*)&YH[kt * 512 + l * 8];
            bf8 al = *(const bf8*)&YL[kt * 512 + l * 8];
            bf8 wh = *(const bf8*)(bh + kt * 32);
            bf8 wl = *(const bf8*)(bl + kt * 32);
            acc = __builtin_amdgcn_mfma_f32_16x16x32_bf16(ah, wh, acc, 0, 0, 0);
            acc = __builtin_amdgcn_mfma_f32_16x16x32_bf16(ah, wl, acc, 0, 0, 0);
            acc = __builtin_amdgcn_mfma_f32_16x16x32_bf16(al, wh, acc, 0, 0, 0);
        }
        float bv = b1[jj];
        #pragma unroll
        for (int r = 0; r < 4; ++r) {
            int row = (l >> 4) * 4 + r;      // D: col=lane&15, row=(lane>>4)*4+reg
            sh_[row * 136 + jj] = fmaxf(acc[r] + bv, 0.f);
        }
    }
    __syncthreads();

    // P2b: pack h fragments (4 k-tiles)
    if (t < 256) {
        int kt = t >> 6, ll = t & 63;
        int row = ll & 15, kb = kt * 32 + (ll >> 4) * 8;
        bf8 vh, vl;
        #pragma unroll
        for (int e = 0; e < 8; ++e) {
            float x = sh_[row * 136 + kb + e];
            unsigned short hh = cv15_f2bf(x);
            vh[e] = (short)hh;
            vl[e] = (short)cv15_f2bf(x - cv15_bf2f(hh));
        }
        *(bf8*)&hfH[kt * 512 + ll * 8] = vh;
        *(bf8*)&hfL[kt * 512 + ll * 8] = vl;
    }
    __syncthreads();

    // P3: adapted = relu(h @ w2 + b2); blend 0.5 into simg. 4 tiles/wave.
    #pragma unroll 1
    for (int tix = w; tix < 32; tix += 8) {
        f4 acc = {0.f, 0.f, 0.f, 0.f};
        const int jj = tix * 16 + (l & 15);
        const unsigned short* bh = w2Th + (size_t)jj * HH + ((l >> 4) * 8);
        const unsigned short* bl = w2Tl + (size_t)jj * HH + ((l >> 4) * 8);
        #pragma unroll
        for (int kt = 0; kt < 4; ++kt) {
            bf8 ah = *(const bf8*)&hfH[kt * 512 + l * 8];
            bf8 al = *(const bf8*)&hfL[kt * 512 + l * 8];
            bf8 wh = *(const bf8*)(bh + kt * 32);
            bf8 wl = *(const bf8*)(bl + kt * 32);
            acc = __builtin_amdgcn_mfma_f32_16x16x32_bf16(ah, wh, acc, 0, 0, 0);
            acc = __builtin_amdgcn_mfma_f32_16x16x32_bf16(ah, wl, acc, 0, 0, 0);
            acc = __builtin_amdgcn_mfma_f32_16x16x32_bf16(al, wh, acc, 0, 0, 0);
        }
        float bv = b2[jj];
        #pragma unroll
        for (int r = 0; r < 4; ++r) {
            int row = (l >> 4) * 4 + r;
            float ad = fmaxf(acc[r] + bv, 0.f);
            float iv = simg[row * IPITCH + jj];
            simg[row * IPITCH + jj] = 0.5f * iv + 0.5f * ad;   // same-thread RMW
        }
    }
    __syncthreads();

    // P3b: repack img_adapted fragments into YH/YL (img frags dead)
    #pragma unroll 1
    for (int p = 0; p < 2; ++p) {
        int kt = p * 8 + w;
        int row = l & 15, kb = kt * 32 + (l >> 4) * 8;
        bf8 vh, vl;
        #pragma unroll
        for (int e = 0; e < 8; ++e) {
            float x = simg[row * IPITCH + kb + e];
            unsigned short hh = cv15_f2bf(x);
            vh[e] = (short)hh;
            vl[e] = (short)cv15_f2bf(x - cv15_bf2f(hh));
        }
        *(bf8*)&YH[kt * 512 + l * 8] = vh;
        *(bf8*)&YL[kt * 512 + l * 8] = vl;
    }
    __syncthreads();

    // P4: sim = img_adapted @ txt. 63 col-tiles, tile % 8 == wave. simg now dead.
    #pragma unroll 1
    for (int tix = w; tix < NT; tix += 8) {
        f4 acc = {0.f, 0.f, 0.f, 0.f};
        const int jj = tix * 16 + (l & 15);
        const unsigned short* bh = txtTh + (size_t)jj * DD + ((l >> 4) * 8);
        const unsigned short* bl = txtTl + (size_t)jj * DD + ((l >> 4) * 8);
        #pragma unroll 4
        for (int kt = 0; kt < 16; ++kt) {
            bf8 ah = *(const bf8*)&YH[kt * 512 + l * 8];
            bf8 al = *(const bf8*)&YL[kt * 512 + l * 8];
            bf8 th = *(const bf8*)(bh + kt * 32);
            bf8 tl2 = *(const bf8*)(bl + kt * 32);
            acc = __builtin_amdgcn_mfma_f32_16x16x32_bf16(ah, th, acc, 0, 0, 0);
            acc = __builtin_amdgcn_mfma_f32_16x16x32_bf16(ah, tl2, acc, 0, 0, 0);
            acc = __builtin_amdgcn_mfma_f32_16x16x32_bf16(al, th, acc, 0, 0, 0);
        }
        #pragma unroll
        for (int r = 0; r < 4; ++r) {
            int row = (l >> 4) * 4 + r;
            ssim[row * SPITCH + jj] = acc[r];
        }
    }
    __syncthreads();

    // ---- validated epilogue (normalize, serial argmax, LSE), 512-thread form ----
    const int myrow = t >> 5;
    const int ln    = t & 31;
    const int tgt   = stgt[myrow];

    {
        float S2 = 0.f;
        #pragma unroll 1
        for (int q = 0; q < 32; ++q) {
            int j = ln + (q << 5);
            if (j < NN) { float v = ssim[myrow * SPITCH + j]; S2 += v * v; }
        }
        red[t] = S2;
        __syncthreads();
        if (ln == 0) {
            float s = 0.f;
            for (int i = 0; i < 32; ++i) s += red[myrow * 32 + i];
            sA[myrow] = 1.0f / sqrtf(s);
        }
        __syncthreads();
    }
    const float a = sA[myrow];
    #pragma unroll 1
    for (int q = 0; q < 32; ++q) {
        int j = ln + (q << 5);
        if (j < NN) ssim[myrow * SPITCH + j] *= a;
    }
    __syncthreads();

    if (t < TM) {   // serial first-occurrence argmax (matches np rule)
        const float* rp = &ssim[t * SPITCH];
        float bm = rp[0]; int bi = 0;
        #pragma unroll 4
        for (int j = 1; j < NN; ++j) {
            float v = rp[j];
            if (v > bm) { bm = v; bi = j; }
        }
        sargmax[t] = bi;
    }
    __syncthreads();

    float mx = -1e30f, vtl = -1e30f;
    #pragma unroll 1
    for (int q = 0; q < 32; ++q) {
        int j = ln + (q << 5);
        if (j < NN) {
            float v = ssim[myrow * SPITCH + j];
            mx = fmaxf(mx, v);
            if (j == tgt) vtl = v;
        }
    }
    red[t] = mx;
    __syncthreads();
    if (ln == 0) {
        float m = -1e30f;
        for (int i = 0; i < 32; ++i) m = fmaxf(m, red[myrow * 32 + i]);
        smax[myrow] = m;
    }
    __syncthreads();
    float rowmax = smax[myrow];

    red[t] = vtl;
    __syncthreads();
    float vt = -1e30f;
    if (ln == 0) {
        for (int i = 0; i < 32; ++i) vt = fmaxf(vt, red[myrow * 32 + i]);
    }
    __syncthreads();

    float E = 0.f;
    #pragma unroll 1
    for (int q = 0; q < 32; ++q) {
        int j = ln + (q << 5);
        if (j < NN) E += expf(ssim[myrow * SPITCH + j] - rowmax);
    }
    red[t] = E;
    __syncthreads();
    if (ln == 0) {
        float Er = 0.f;
        for (int i = 0; i < 32; ++i) Er += red[myrow * 32 + i];
        srow[myrow][0] = (rowmax - vt) + logf(Er);
        srow[myrow][1] = (sargmax[myrow] == tgt) ? 1.f : 0.f;
    }
    __syncthreads();
    if (t == 0) {
        float ls = 0.f, ac = 0.f;
        #pragma unroll
        for (int r = 0; r < TM; ++r) { ls += srow[r][0]; ac += srow[r][1]; }
        partials[blk * 2 + 0] = ls;
        partials[blk * 2 + 1] = ac;
    }
}

__global__ __launch_bounds__(256)
void cv15_final(const float* __restrict__ partials, float* __restrict__ out)
{
    __shared__ float fb[512];
    float ls = 0.f, ac = 0.f;
    #pragma unroll 1
    for (int i = threadIdx.x; i < NBLK; i += 256) {
        ls += partials[2 * i];
        ac += partials[2 * i + 1];
    }
    fb[threadIdx.x] = ls;
    fb[256 + threadIdx.x] = ac;
    __syncthreads();
    if (threadIdx.x == 0) {
        float L = 0.f, A = 0.f;
        for (int i = 0; i < 256; ++i) { L += fb[i]; A += fb[256 + i]; }
        out[0] = L * (1.0f / (float)BSZ);   // mean NLL (float32; validated)
        out[1] = A;                          // accuracy count (float32; validated)
    }
}

// ---------- fallback: validated fp32 path (cv14), used if ws too small ----------
__global__ __launch_bounds__(256)
void cv15_fb_main(const float* __restrict__ img, const float* __restrict__ txt,
                  const float* __restrict__ w1, const float* __restrict__ b1,
                  const float* __restrict__ w2, const float* __restrict__ b2,
                  const unsigned* __restrict__ target, float* __restrict__ partials)
{
    __shared__ __align__(16) float arena[16000];
    __shared__ float red[256];
    __shared__ float smax[TM], sA[TM], srow[TM][2];
    __shared__ int   stgt[TM], sargmax[TM], tflag;

    const int t = threadIdx.x, blk = blockIdx.x, row0 = blk * TM;
    if (t == 0) {
        int allz = 1, small = 1;
        #pragma unroll 1
        for (int i = 0; i < 32; ++i) { allz &= (target[2*i+1]==0u); small &= (target[2*i]<1000000u); }
        tflag = (allz && small) ? 1 : 0;
    }
    __syncthreads();
    if (t < TM) {
        int r = row0 + t;
        int tg = (int)(tflag ? target[2*r] : target[r]);
        stgt[t] = tg < 0 ? 0 : (tg > NN-1 ? NN-1 : tg);
    }
    float* simg = arena; float* sh = arena + 8192;
    {
        const float4* src = (const float4*)(img + (size_t)row0 * DD);
        float4* dst = (float4*)simg;
        #pragma unroll
        for (int i = 0; i < 8; ++i) dst[t + i*256] = src[t + i*256];
    }
    __syncthreads();
    {
        const int c = t & 127, rh = t >> 7;
        float acc[8];
        #pragma unroll
        for (int i = 0; i < 8; ++i) acc[i] = 0.f;
        #pragma unroll 1
        for (int k = 0; k < DD; k += 4) {
            float w0=w1[(k+0)*HH+c], w1_=w1[(k+1)*HH+c], w2_=w1[(k+2)*HH+c], w3=w1[(k+3)*HH+c];
            #pragma unroll
            for (int i = 0; i < 8; ++i) {
                const float4 s = *(const float4*)&simg[(rh*8+i)*DD + k];
                acc[i] = fmaf(s.x,w0,fmaf(s.y,w1_,fmaf(s.z,w2_,fmaf(s.w,w3,acc[i]))));
            }
        }
        float bb = b1[c];
        #pragma unroll
        for (int i = 0; i < 8; ++i) sh[(rh*8+i)*HH + c] = fmaxf(acc[i]+bb, 0.f);
    }
    __syncthreads();
    {
        const int c0 = t, c1 = t + 256;
        float accA[TM], accB[TM];
        #pragma unroll
        for (int r = 0; r < TM; ++r) { accA[r]=0.f; accB[r]=0.f; }
        #pragma unroll 1
        for (int k = 0; k < HH; k += 4) {
            float wa[4], wb[4];
            #pragma unroll
            for (int u = 0; u < 4; ++u) { wa[u]=w2[(k+u)*DD+c0]; wb[u]=w2[(k+u)*DD+c1]; }
            #pragma unroll
            for (int r = 0; r < TM; ++r) {
                const float4 hv = *(const float4*)&sh[r*HH + k];
                accA[r]=fmaf(hv.x,wa[0],fmaf(hv.y,wa[1],fmaf(hv.z,wa[2],fmaf(hv.w,wa[3],accA[r]))));
                accB[r]=fmaf(hv.x,wb[0],fmaf(hv.y,wb[1],fmaf(hv.z,wb[2],fmaf(hv.w,wb[3],accB[r]))));
            }
        }
        const float ba = b2[c0], bb = b2[c1];
        #pragma unroll
        for (int r = 0; r < TM; ++r) {
            simg[r*DD+c0] = 0.5f*simg[r*DD+c0] + 0.5f*fmaxf(accA[r]+ba, 0.f);
            simg[r*DD+c1] = 0.5f*simg[r*DD+c1] + 0.5f*fmaxf(accB[r]+bb, 0.f);
        }
    }
    __syncthreads();
    float acc4[4][TM];
    #pragma unroll
    for (int c = 0; c < 4; ++c)
        #pragma unroll
        for (int r = 0; r < TM; ++r) acc4[c][r] = 0.f;
    const bool v3 = (768 + t) < NN;
    #pragma unroll 1
    for (int k = 0; k < DD; k += 4) {
        float tx[4][4];
        #pragma unroll
        for (int u = 0; u < 4; ++u) {
            const float* tp = txt + (size_t)(k+u)*NN;
            tx[0][u]=tp[t]; tx[1][u]=tp[256+t]; tx[2][u]=tp[512+t]; tx[3][u]=v3?tp[768+t]:0.f;
        }
        #pragma unroll
        for (int half = 0; half < 2; ++half) {
            float4 sv[8];
            #pragma unroll
            for (int i = 0; i < 8; ++i) sv[i] = *(const float4*)&simg[(half*8+i)*DD + k];
            #pragma unroll
            for (int i = 0; i < 8; ++i) {
                const int r = half*8 + i;
                #pragma unroll
                for (int c = 0; c < 4; ++c)
                    acc4[c][r]=fmaf(sv[i].x,tx[c][0],fmaf(sv[i].y,tx[c][1],fmaf(sv[i].z,tx[c][2],fmaf(sv[i].w,tx[c][3],acc4[c][r]))));
            }
        }
    }
    __syncthreads();
    #pragma unroll
    for (int c = 0; c < 4; ++c) {
        const int col = c*256 + t;
        if (col < NN)
            #pragma unroll
            for (int r = 0; r < TM; ++r) arena[r*NN + col] = acc4[c][r];
    }
    __syncthreads();
    const int myrow = t >> 4, ln = t & 15, tgt = stgt[myrow];
    {
        float S2 = 0.f;
        #pragma unroll 1
        for (int q = 0; q < 63; ++q) { int j = ln + (q<<4); if (j < NN) { float v = arena[myrow*NN+j]; S2 += v*v; } }
        red[t] = S2; __syncthreads();
        if (ln == 0) { float s=0.f; for (int i=0;i<16;++i) s+=red[myrow*16+i]; sA[myrow]=1.0f/sqrtf(s); }
        __syncthreads();
    }
    const float a = sA[myrow];
    #pragma unroll 1
    for (int q = 0; q < 63; ++q) { int j = ln + (q<<4); if (j < NN) arena[myrow*NN+j] *= a; }
    __syncthreads();
    if (t < TM) {
        const float* rp = &arena[t*NN];
        float bm = rp[0]; int bi = 0;
        #pragma unroll 4
        for (int j = 1; j < NN; ++j) { float v = rp[j]; if (v > bm) { bm = v; bi = j; } }
        sargmax[t] = bi;
    }
    __syncthreads();
    float mx = -1e30f, vtl = -1e30f;
    #pragma unroll 1
    for (int q = 0; q < 63; ++q) {
        int j = ln + (q<<4);
        if (j < NN) { float v = arena[myrow*NN+j]; mx = fmaxf(mx, v); if (j == tgt) vtl = v; }
    }
    red[t] = mx; __syncthreads();
    float rowmax = -1e30f;
    if (ln == 0) { for (int i=0;i<16;++i) rowmax = fmaxf(rowmax, red[myrow*16+i]); smax[myrow] = rowmax; }
    __syncthreads();
    rowmax = smax[myrow];
    red[t] = vtl; __syncthreads();
    float vt = -1e30f;
    if (ln == 0) { for (int i=0;i<16;++i) vt = fmaxf(vt, red[myrow*16+i]); }
    __syncthreads();
    float E = 0.f;
    #pragma unroll 1
    for (int q = 0; q < 63; ++q) { int j = ln + (q<<4); if (j < NN) E += expf(arena[myrow*NN+j] - rowmax); }
    red[t] = E; __syncthreads();
    if (ln == 0) {
        float Er = 0.f; for (int i=0;i<16;++i) Er += red[myrow*16+i];
        srow[myrow][0] = (rowmax - vt) + logf(Er);
        srow[myrow][1] = (sargmax[myrow] == tgt) ? 1.f : 0.f;
    }
    __syncthreads();
    if (t == 0) {
        float ls = 0.f, ac = 0.f;
        #pragma unroll
        for (int r = 0; r < TM; ++r) { ls += srow[r][0]; ac += srow[r][1]; }
        partials[blk*2+0] = ls; partials[blk*2+1] = ac;
    }
}

extern "C" void kernel_launch(void* const* d_in, const int* in_sizes, int n_in,
                              void* d_out, int out_size, void* d_ws, size_t ws_size,
                              hipStream_t stream)
{
    const void *img = nullptr, *txt = nullptr, *w1 = nullptr, *w2 = nullptr;
    const void *b1 = nullptr, *b2 = nullptr, *tgt = nullptr;
    for (int i = 0; i < n_in; ++i) {
        long s = in_sizes[i];
        if      (s == (long)BSZ * DD) img = d_in[i];
        else if (s == (long)DD * NN)  txt = d_in[i];
        else if (s == (long)DD * HH) { if (!w1) w1 = d_in[i]; else w2 = d_in[i]; }
        else if (s == HH)  b1 = d_in[i];
        else if (s == DD)  b2 = d_in[i];
        else if (s == BSZ) tgt = d_in[i];
    }
    if (!img || !txt || !w1 || !w2 || !b1 || !b2 || !tgt) {
        img = d_in[0]; txt = d_in[1]; w1 = d_in[2]; b1 = d_in[3];
        w2 = d_in[4]; b2 = d_in[5]; tgt = d_in[8];
    }

    // workspace carve (shorts): txtT 2x 1024*512, w1T 2x 128*512, w2T 2x 512*128
    const size_t nTxt = (size_t)1024 * 512, nW = (size_t)128 * 512;
    const size_t needBytes = (2 * nTxt + 4 * nW) * 2 + 16384 + 256;

    if (ws_size >= needBytes) {
        unsigned short* txtTh = (unsigned short*)d_ws;
        unsigned short* txtTl = txtTh + nTxt;
        unsigned short* w1Th  = txtTl + nTxt;
        unsigned short* w1Tl  = w1Th + nW;
        unsigned short* w2Th  = w1Tl + nW;
        unsigned short* w2Tl  = w2Th + nW;
        float* partials = (float*)(w2Tl + nW);

        cv15_prep_txt<<<1024, 256, 0, stream>>>((const float*)txt, txtTh, txtTl);
        cv15_prep_w1<<<128, 256, 0, stream>>>((const float*)w1, w1Th, w1Tl);
        cv15_prep_w2<<<512, 128, 0, stream>>>((const float*)w2, w2Th, w2Tl);
        cv15_main<<<NBLK, 512, 0, stream>>>((const float*)img, (const float*)b1,
                                            (const float*)b2, txtTh, txtTl,
                                            w1Th, w1Tl, w2Th, w2Tl,
                                            (const unsigned*)tgt, partials);
        cv15_final<<<1, 256, 0, stream>>>(partials, (float*)d_out);
    } else {
        float* partials = (float*)d_ws;
        cv15_fb_main<<<NBLK, 256, 0, stream>>>((const float*)img, (const float*)txt,
                                               (const float*)w1, (const float*)b1,
                                               (const float*)w2, (const float*)b2,
                                               (const unsigned*)tgt, partials);
        cv15_final<<<1, 256, 0, stream>>>(partials, (float*)d_out);
    }
}

// Round 16
// 593.532 us; speedup vs baseline: 1.5893x; 1.5893x over previous
//
#include <hip/hip_runtime.h>
#include <math.h>

#define BSZ   32768
#define DD    512
#define HH    128
#define NN    1000
#define TM    16
#define NBLK  (BSZ / TM)   // 2048
#define NT    63           // 16-wide col tiles covering 1008 >= 1000
#define IPITCH 520         // simg row pitch (floats)

typedef short  bf8 __attribute__((ext_vector_type(8)));
typedef float  f4  __attribute__((ext_vector_type(4)));

__device__ __forceinline__ unsigned short cv16_f2bf(float f) {
    unsigned u = __float_as_uint(f);
    u = u + 0x7FFF + ((u >> 16) & 1);
    return (unsigned short)(u >> 16);
}
__device__ __forceinline__ float cv16_bf2f(unsigned short h) {
    return __uint_as_float(((unsigned)h) << 16);
}

// ---------- pre-kernels: transpose + bf16 hi/lo split (validated r15) ----------
__global__ void cv16_prep_txt(const float* __restrict__ txt,
                              unsigned short* __restrict__ th,
                              unsigned short* __restrict__ tl)
{
    int j = blockIdx.x;                       // 0..1023 (cols, padded with zeros)
    for (int k = threadIdx.x; k < DD; k += blockDim.x) {
        float v = (j < NN) ? txt[(size_t)k * NN + j] : 0.f;
        unsigned short h = cv16_f2bf(v);
        unsigned short l = cv16_f2bf(v - cv16_bf2f(h));
        th[(size_t)j * DD + k] = h;
        tl[(size_t)j * DD + k] = l;
    }
}
__global__ void cv16_prep_w1(const float* __restrict__ w1,
                             unsigned short* __restrict__ th,
                             unsigned short* __restrict__ tl)
{
    int j = blockIdx.x;                       // 0..127
    for (int k = threadIdx.x; k < DD; k += blockDim.x) {
        float v = w1[(size_t)k * HH + j];
        unsigned short h = cv16_f2bf(v);
        unsigned short l = cv16_f2bf(v - cv16_bf2f(h));
        th[(size_t)j * DD + k] = h;
        tl[(size_t)j * DD + k] = l;
    }
}
__global__ void cv16_prep_w2(const float* __restrict__ w2,
                             unsigned short* __restrict__ th,
                             unsigned short* __restrict__ tl)
{
    int j = blockIdx.x;                       // 0..511
    for (int k = threadIdx.x; k < HH; k += blockDim.x) {
        float v = w2[(size_t)k * DD + j];
        unsigned short h = cv16_f2bf(v);
        unsigned short l = cv16_f2bf(v - cv16_bf2f(h));
        th[(size_t)j * HH + k] = h;
        tl[(size_t)j * HH + k] = l;
    }
}

#define MFMA16(a, b, c) __builtin_amdgcn_mfma_f32_16x16x32_bf16((a), (b), (c), 0, 0, 0)

// ---------- main fused kernel: sim in REGISTERS, 2 blocks/CU target ----------
__global__ __launch_bounds__(512, 4)
void cv16_main(const float* __restrict__ img,
               const float* __restrict__ b1,
               const float* __restrict__ b2,
               const unsigned short* __restrict__ txtTh,
               const unsigned short* __restrict__ txtTl,
               const unsigned short* __restrict__ w1Th,
               const unsigned short* __restrict__ w1Tl,
               const unsigned short* __restrict__ w2Th,
               const unsigned short* __restrict__ w2Tl,
               const unsigned* __restrict__ target,
               float* __restrict__ partials)
{
    __shared__ float          simg[16 * IPITCH];    // 33.3 KB fp32 img / img_adapted
    __shared__ unsigned short YH[16 * 512];         // 16 KB A-frag hi (hf aliased in)
    __shared__ unsigned short YL[16 * 512];         // 16 KB A-frag lo
    __shared__ float          sh_[16 * 136];        // 8.7 KB h fp32
    __shared__ float          red[512];             // 2 KB fold area (4 stats x 16r x 8w)
    __shared__ float          sAr[TM], sMx[TM], sVt[TM];
    __shared__ float          srow[TM][2];
    __shared__ int            stgt[TM];
    __shared__ int            tflag;

    unsigned short* hfH = YH;                       // alias: Y dead between P2 and P3b
    unsigned short* hfL = YH + 2048;

    const int t    = threadIdx.x;
    const int w    = t >> 6;         // wave 0..7
    const int l    = t & 63;         // lane
    const int blk  = blockIdx.x;
    const int row0 = blk * TM;

    // targets (validated probe)
    if (t == 0) {
        int allz = 1, small = 1;
        #pragma unroll 1
        for (int i = 0; i < 32; ++i) {
            allz  &= (target[2 * i + 1] == 0u);
            small &= (target[2 * i] < 1000000u);
        }
        tflag = (allz && small) ? 1 : 0;
    }
    __syncthreads();
    if (t < TM) {
        int r = row0 + t;
        int tg = (int)(tflag ? target[2 * r] : target[r]);
        if (tg < 0) tg = 0;
        if (tg > NN - 1) tg = NN - 1;
        stgt[t] = tg;
    }

    // P1: stage img fp32 tile (validated)
    {
        const float4* src = (const float4*)(img + (size_t)row0 * DD);
        #pragma unroll 1
        for (int i = t; i < 2048; i += 512) {
            float4 v = src[i];
            int r = (i * 4) >> 9;
            int c = (i * 4) & 511;
            *(float4*)&simg[r * IPITCH + c] = v;
        }
    }
    __syncthreads();

    // P1b: pack img A-fragments hi/lo (validated)
    #pragma unroll 1
    for (int p = 0; p < 2; ++p) {
        int kt = p * 8 + w;
        int row = l & 15, kb = kt * 32 + (l >> 4) * 8;
        bf8 vh, vl;
        #pragma unroll
        for (int e = 0; e < 8; ++e) {
            float x = simg[row * IPITCH + kb + e];
            unsigned short hh = cv16_f2bf(x);
            vh[e] = (short)hh;
            vl[e] = (short)cv16_f2bf(x - cv16_bf2f(hh));
        }
        *(bf8*)&YH[kt * 512 + l * 8] = vh;
        *(bf8*)&YL[kt * 512 + l * 8] = vl;
    }
    __syncthreads();

    // P2: h = relu(img @ w1 + b1)  (validated)
    {
        f4 acc = {0.f, 0.f, 0.f, 0.f};
        const int jj = w * 16 + (l & 15);
        const unsigned short* bh = w1Th + (size_t)jj * DD + ((l >> 4) * 8);
        const unsigned short* bl = w1Tl + (size_t)jj * DD + ((l >> 4) * 8);
        #pragma unroll 4
        for (int kt = 0; kt < 16; ++kt) {
            bf8 ah = *(const bf8*)&YH[kt * 512 + l * 8];
            bf8 al = *(const bf8*)&YL[kt * 512 + l * 8];
            bf8 wh = *(const bf8*)(bh + kt * 32);
            bf8 wl = *(const bf8*)(bl + kt * 32);
            acc = MFMA16(ah, wh, acc);
            acc = MFMA16(ah, wl, acc);
            acc = MFMA16(al, wh, acc);
        }
        float bv = b1[jj];
        #pragma unroll
        for (int r = 0; r < 4; ++r) {
            int row = (l >> 4) * 4 + r;
            sh_[row * 136 + jj] = fmaxf(acc[r] + bv, 0.f);
        }
    }
    __syncthreads();

    // P2b: pack h fragments into aliased hf region (Y img-frags dead)
    if (t < 256) {
        int kt = t >> 6, ll = t & 63;
        int row = ll & 15, kb = kt * 32 + (ll >> 4) * 8;
        bf8 vh, vl;
        #pragma unroll
        for (int e = 0; e < 8; ++e) {
            float x = sh_[row * 136 + kb + e];
            unsigned short hh = cv16_f2bf(x);
            vh[e] = (short)hh;
            vl[e] = (short)cv16_f2bf(x - cv16_bf2f(hh));
        }
        *(bf8*)&hfH[kt * 512 + ll * 8] = vh;
        *(bf8*)&hfL[kt * 512 + ll * 8] = vl;
    }
    __syncthreads();

    // P3: adapted = relu(h @ w2 + b2); blend 0.5 into simg (validated)
    #pragma unroll 1
    for (int tix = w; tix < 32; tix += 8) {
        f4 acc = {0.f, 0.f, 0.f, 0.f};
        const int jj = tix * 16 + (l & 15);
        const unsigned short* bh = w2Th + (size_t)jj * HH + ((l >> 4) * 8);
        const unsigned short* bl = w2Tl + (size_t)jj * HH + ((l >> 4) * 8);
        #pragma unroll
        for (int kt = 0; kt < 4; ++kt) {
            bf8 ah = *(const bf8*)&hfH[kt * 512 + l * 8];
            bf8 al = *(const bf8*)&hfL[kt * 512 + l * 8];
            bf8 wh = *(const bf8*)(bh + kt * 32);
            bf8 wl = *(const bf8*)(bl + kt * 32);
            acc = MFMA16(ah, wh, acc);
            acc = MFMA16(ah, wl, acc);
            acc = MFMA16(al, wh, acc);
        }
        float bv = b2[jj];
        #pragma unroll
        for (int r = 0; r < 4; ++r) {
            int row = (l >> 4) * 4 + r;
            float ad = fmaxf(acc[r] + bv, 0.f);
            float iv = simg[row * IPITCH + jj];
            simg[row * IPITCH + jj] = 0.5f * iv + 0.5f * ad;
        }
    }
    __syncthreads();

    // P3b: repack img_adapted fragments (validated; overwrites hf alias too)
    #pragma unroll 1
    for (int p = 0; p < 2; ++p) {
        int kt = p * 8 + w;
        int row = l & 15, kb = kt * 32 + (l >> 4) * 8;
        bf8 vh, vl;
        #pragma unroll
        for (int e = 0; e < 8; ++e) {
            float x = simg[row * IPITCH + kb + e];
            unsigned short hh = cv16_f2bf(x);
            vh[e] = (short)hh;
            vl[e] = (short)cv16_f2bf(x - cv16_bf2f(hh));
        }
        *(bf8*)&YH[kt * 512 + l * 8] = vh;
        *(bf8*)&YL[kt * 512 + l * 8] = vl;
    }
    __syncthreads();

    // P4: sim tiles in REGISTERS. 8 tiles/wave, 2 interleaved MFMA chains.
    // simacc[i]: tix = w + (i>>1)*16 + (i&1)*8  (monotone in i per lane)
    f4 simacc[8];
    #pragma unroll
    for (int i = 0; i < 8; ++i) simacc[i] = (f4){0.f, 0.f, 0.f, 0.f};

    #pragma unroll
    for (int tp = 0; tp < 4; ++tp) {
        const int tixA = w + tp * 16;
        const int tixB = tixA + 8;          // tile 63 = zero-padded cols, masked later
        const unsigned short* bhA = txtTh + (size_t)(tixA * 16 + (l & 15)) * DD + ((l >> 4) * 8);
        const unsigned short* blA = txtTl + (size_t)(tixA * 16 + (l & 15)) * DD + ((l >> 4) * 8);
        const unsigned short* bhB = txtTh + (size_t)(tixB * 16 + (l & 15)) * DD + ((l >> 4) * 8);
        const unsigned short* blB = txtTl + (size_t)(tixB * 16 + (l & 15)) * DD + ((l >> 4) * 8);
        #pragma unroll 4
        for (int kt = 0; kt < 16; ++kt) {
            bf8 ah  = *(const bf8*)&YH[kt * 512 + l * 8];
            bf8 al  = *(const bf8*)&YL[kt * 512 + l * 8];
            bf8 wAh = *(const bf8*)(bhA + kt * 32);
            bf8 wAl = *(const bf8*)(blA + kt * 32);
            bf8 wBh = *(const bf8*)(bhB + kt * 32);
            bf8 wBl = *(const bf8*)(blB + kt * 32);
            simacc[tp * 2]     = MFMA16(ah, wAh, simacc[tp * 2]);
            simacc[tp * 2 + 1] = MFMA16(ah, wBh, simacc[tp * 2 + 1]);
            simacc[tp * 2]     = MFMA16(ah, wAl, simacc[tp * 2]);
            simacc[tp * 2 + 1] = MFMA16(ah, wBl, simacc[tp * 2 + 1]);
            simacc[tp * 2]     = MFMA16(al, wAh, simacc[tp * 2]);
            simacc[tp * 2 + 1] = MFMA16(al, wBh, simacc[tp * 2 + 1]);
        }
    }

    // ---- epilogue from registers: stats -> shfl reduce -> LDS fold ----
    // value (row=(l>>4)*4+r, col=tix*16+(l&15)); same math/order as r15 (bit-identical v)
    float s2v[4] = {0.f, 0.f, 0.f, 0.f};
    float mxv[4] = {-1e30f, -1e30f, -1e30f, -1e30f};
    float vtv[4] = {-1e30f, -1e30f, -1e30f, -1e30f};
    int   mxi[4] = {0x7fffffff, 0x7fffffff, 0x7fffffff, 0x7fffffff};

    #pragma unroll
    for (int i = 0; i < 8; ++i) {
        const int tix = w + (i >> 1) * 16 + (i & 1) * 8;
        const int col = tix * 16 + (l & 15);
        const bool ok = col < NN;
        #pragma unroll
        for (int r = 0; r < 4; ++r) {
            float v = simacc[i][r];
            if (ok) {
                s2v[r] += v * v;
                if (v > mxv[r] || (v == mxv[r] && col < mxi[r])) { mxv[r] = v; mxi[r] = col; }
                int row = (l >> 4) * 4 + r;
                if (col == stgt[row]) vtv[r] = v;
            }
        }
    }
    #pragma unroll
    for (int m = 1; m < 16; m <<= 1) {
        #pragma unroll
        for (int r = 0; r < 4; ++r) {
            s2v[r] += __shfl_xor(s2v[r], m);
            float ov = __shfl_xor(mxv[r], m);
            int   oi = __shfl_xor(mxi[r], m);
            if (ov > mxv[r] || (ov == mxv[r] && oi < mxi[r])) { mxv[r] = ov; mxi[r] = oi; }
            vtv[r] = fmaxf(vtv[r], __shfl_xor(vtv[r], m));
        }
    }
    if ((l & 15) == 0) {
        #pragma unroll
        for (int r = 0; r < 4; ++r) {
            int row = (l >> 4) * 4 + r;
            red[  0 + row * 8 + w] = s2v[r];
            red[128 + row * 8 + w] = mxv[r];
            red[256 + row * 8 + w] = __int_as_float(mxi[r]);
            red[384 + row * 8 + w] = vtv[r];
        }
    }
    __syncthreads();
    if (t < TM) {
        float S2 = 0.f, MX = -1e30f, VT = -1e30f;
        int MI = 0x7fffffff;
        #pragma unroll
        for (int ww = 0; ww < 8; ++ww) {
            S2 += red[t * 8 + ww];
            float ov = red[128 + t * 8 + ww];
            int   oi = __float_as_int(red[256 + t * 8 + ww]);
            if (ov > MX || (ov == MX && oi < MI)) { MX = ov; MI = oi; }
            VT = fmaxf(VT, red[384 + t * 8 + ww]);
        }
        sAr[t] = 1.0f / sqrtf(S2);
        sMx[t] = MX;
        sVt[t] = VT;
        srow[t][1] = (MI == stgt[t]) ? 1.f : 0.f;
    }
    __syncthreads();

    // E pass from registers
    float es[4] = {0.f, 0.f, 0.f, 0.f};
    #pragma unroll
    for (int i = 0; i < 8; ++i) {
        const int tix = w + (i >> 1) * 16 + (i & 1) * 8;
        const int col = tix * 16 + (l & 15);
        const bool ok = col < NN;
        #pragma unroll
        for (int r = 0; r < 4; ++r) {
            if (ok) {
                int row = (l >> 4) * 4 + r;
                es[r] += expf((simacc[i][r] - sMx[row]) * sAr[row]);
            }
        }
    }
    #pragma unroll
    for (int m = 1; m < 16; m <<= 1) {
        #pragma unroll
        for (int r = 0; r < 4; ++r) es[r] += __shfl_xor(es[r], m);
    }
    if ((l & 15) == 0) {
        #pragma unroll
        for (int r = 0; r < 4; ++r) {
            int row = (l >> 4) * 4 + r;
            red[row * 8 + w] = es[r];
        }
    }
    __syncthreads();
    if (t < TM) {
        float E = 0.f;
        #pragma unroll
        for (int ww = 0; ww < 8; ++ww) E += red[t * 8 + ww];
        srow[t][0] = (sMx[t] - sVt[t]) * sAr[t] + logf(E);
    }
    __syncthreads();
    if (t == 0) {
        float ls = 0.f, ac = 0.f;
        #pragma unroll
        for (int r = 0; r < TM; ++r) { ls += srow[r][0]; ac += srow[r][1]; }
        partials[blk * 2 + 0] = ls;
        partials[blk * 2 + 1] = ac;
    }
}

__global__ __launch_bounds__(256)
void cv16_final(const float* __restrict__ partials, float* __restrict__ out)
{
    __shared__ float fb[512];
    float ls = 0.f, ac = 0.f;
    #pragma unroll 1
    for (int i = threadIdx.x; i < NBLK; i += 256) {
        ls += partials[2 * i];
        ac += partials[2 * i + 1];
    }
    fb[threadIdx.x] = ls;
    fb[256 + threadIdx.x] = ac;
    __syncthreads();
    if (threadIdx.x == 0) {
        float L = 0.f, A = 0.f;
        for (int i = 0; i < 256; ++i) { L += fb[i]; A += fb[256 + i]; }
        out[0] = L * (1.0f / (float)BSZ);   // mean NLL (float32; validated)
        out[1] = A;                          // accuracy count (float32; validated)
    }
}

// ---------- fallback: validated fp32 path (unchanged from r14/r15) ----------
__global__ __launch_bounds__(256)
void cv16_fb_main(const float* __restrict__ img, const float* __restrict__ txt,
                  const float* __restrict__ w1, const float* __restrict__ b1,
                  const float* __restrict__ w2, const float* __restrict__ b2,
                  const unsigned* __restrict__ target, float* __restrict__ partials)
{
    __shared__ __align__(16) float arena[16000];
    __shared__ float red[256];
    __shared__ float smax[TM], sA[TM], srow[TM][2];
    __shared__ int   stgt[TM], sargmax[TM], tflag;

    const int t = threadIdx.x, blk = blockIdx.x, row0 = blk * TM;
    if (t == 0) {
        int allz = 1, small = 1;
        #pragma unroll 1
        for (int i = 0; i < 32; ++i) { allz &= (target[2*i+1]==0u); small &= (target[2*i]<1000000u); }
        tflag = (allz && small) ? 1 : 0;
    }
    __syncthreads();
    if (t < TM) {
        int r = row0 + t;
        int tg = (int)(tflag ? target[2*r] : target[r]);
        stgt[t] = tg < 0 ? 0 : (tg > NN-1 ? NN-1 : tg);
    }
    float* simg = arena; float* sh = arena + 8192;
    {
        const float4* src = (const float4*)(img + (size_t)row0 * DD);
        float4* dst = (float4*)simg;
        #pragma unroll
        for (int i = 0; i < 8; ++i) dst[t + i*256] = src[t + i*256];
    }
    __syncthreads();
    {
        const int c = t & 127, rh = t >> 7;
        float acc[8];
        #pragma unroll
        for (int i = 0; i < 8; ++i) acc[i] = 0.f;
        #pragma unroll 1
        for (int k = 0; k < DD; k += 4) {
            float w0=w1[(k+0)*HH+c], w1_=w1[(k+1)*HH+c], w2_=w1[(k+2)*HH+c], w3=w1[(k+3)*HH+c];
            #pragma unroll
            for (int i = 0; i < 8; ++i) {
                const float4 s = *(const float4*)&simg[(rh*8+i)*DD + k];
                acc[i] = fmaf(s.x,w0,fmaf(s.y,w1_,fmaf(s.z,w2_,fmaf(s.w,w3,acc[i]))));
            }
        }
        float bb = b1[c];
        #pragma unroll
        for (int i = 0; i < 8; ++i) sh[(rh*8+i)*HH + c] = fmaxf(acc[i]+bb, 0.f);
    }
    __syncthreads();
    {
        const int c0 = t, c1 = t + 256;
        float accA[TM], accB[TM];
        #pragma unroll
        for (int r = 0; r < TM; ++r) { accA[r]=0.f; accB[r]=0.f; }
        #pragma unroll 1
        for (int k = 0; k < HH; k += 4) {
            float wa[4], wb[4];
            #pragma unroll
            for (int u = 0; u < 4; ++u) { wa[u]=w2[(k+u)*DD+c0]; wb[u]=w2[(k+u)*DD+c1]; }
            #pragma unroll
            for (int r = 0; r < TM; ++r) {
                const float4 hv = *(const float4*)&sh[r*HH + k];
                accA[r]=fmaf(hv.x,wa[0],fmaf(hv.y,wa[1],fmaf(hv.z,wa[2],fmaf(hv.w,wa[3],accA[r]))));
                accB[r]=fmaf(hv.x,wb[0],fmaf(hv.y,wb[1],fmaf(hv.z,wb[2],fmaf(hv.w,wb[3],accB[r]))));
            }
        }
        const float ba = b2[c0], bb = b2[c1];
        #pragma unroll
        for (int r = 0; r < TM; ++r) {
            simg[r*DD+c0] = 0.5f*simg[r*DD+c0] + 0.5f*fmaxf(accA[r]+ba, 0.f);
            simg[r*DD+c1] = 0.5f*simg[r*DD+c1] + 0.5f*fmaxf(accB[r]+bb, 0.f);
        }
    }
    __syncthreads();
    float acc4[4][TM];
    #pragma unroll
    for (int c = 0; c < 4; ++c)
        #pragma unroll
        for (int r = 0; r < TM; ++r) acc4[c][r] = 0.f;
    const bool v3 = (768 + t) < NN;
    #pragma unroll 1
    for (int k = 0; k < DD; k += 4) {
        float tx[4][4];
        #pragma unroll
        for (int u = 0; u < 4; ++u) {
            const float* tp = txt + (size_t)(k+u)*NN;
            tx[0][u]=tp[t]; tx[1][u]=tp[256+t]; tx[2][u]=tp[512+t]; tx[3][u]=v3?tp[768+t]:0.f;
        }
        #pragma unroll
        for (int half = 0; half < 2; ++half) {
            float4 sv[8];
            #pragma unroll
            for (int i = 0; i < 8; ++i) sv[i] = *(const float4*)&simg[(half*8+i)*DD + k];
            #pragma unroll
            for (int i = 0; i < 8; ++i) {
                const int r = half*8 + i;
                #pragma unroll
                for (int c = 0; c < 4; ++c)
                    acc4[c][r]=fmaf(sv[i].x,tx[c][0],fmaf(sv[i].y,tx[c][1],fmaf(sv[i].z,tx[c][2],fmaf(sv[i].w,tx[c][3],acc4[c][r]))));
            }
        }
    }
    __syncthreads();
    #pragma unroll
    for (int c = 0; c < 4; ++c) {
        const int col = c*256 + t;
        if (col < NN)
            #pragma unroll
            for (int r = 0; r < TM; ++r) arena[r*NN + col] = acc4[c][r];
    }
    __syncthreads();
    const int myrow = t >> 4, ln = t & 15, tgt = stgt[myrow];
    {
        float S2 = 0.f;
        #pragma unroll 1
        for (int q = 0; q < 63; ++q) { int j = ln + (q<<4); if (j < NN) { float v = arena[myrow*NN+j]; S2 += v*v; } }
        red[t] = S2; __syncthreads();
        if (ln == 0) { float s=0.f; for (int i=0;i<16;++i) s+=red[myrow*16+i]; sA[myrow]=1.0f/sqrtf(s); }
        __syncthreads();
    }
    const float a = sA[myrow];
    #pragma unroll 1
    for (int q = 0; q < 63; ++q) { int j = ln + (q<<4); if (j < NN) arena[myrow*NN+j] *= a; }
    __syncthreads();
    if (t < TM) {
        const float* rp = &arena[t*NN];
        float bm = rp[0]; int bi = 0;
        #pragma unroll 4
        for (int j = 1; j < NN; ++j) { float v = rp[j]; if (v > bm) { bm = v; bi = j; } }
        sargmax[t] = bi;
    }
    __syncthreads();
    float mx = -1e30f, vtl = -1e30f;
    #pragma unroll 1
    for (int q = 0; q < 63; ++q) {
        int j = ln + (q<<4);
        if (j < NN) { float v = arena[myrow*NN+j]; mx = fmaxf(mx, v); if (j == tgt) vtl = v; }
    }
    red[t] = mx; __syncthreads();
    float rowmax = -1e30f;
    if (ln == 0) { for (int i=0;i<16;++i) rowmax = fmaxf(rowmax, red[myrow*16+i]); smax[myrow] = rowmax; }
    __syncthreads();
    rowmax = smax[myrow];
    red[t] = vtl; __syncthreads();
    float vt = -1e30f;
    if (ln == 0) { for (int i=0;i<16;++i) vt = fmaxf(vt, red[myrow*16+i]); }
    __syncthreads();
    float E = 0.f;
    #pragma unroll 1
    for (int q = 0; q < 63; ++q) { int j = ln + (q<<4); if (j < NN) E += expf(arena[myrow*NN+j] - rowmax); }
    red[t] = E; __syncthreads();
    if (ln == 0) {
        float Er = 0.f; for (int i=0;i<16;++i) Er += red[myrow*16+i];
        srow[myrow][0] = (rowmax - vt) + logf(Er);
        srow[myrow][1] = (sargmax[myrow] == tgt) ? 1.f : 0.f;
    }
    __syncthreads();
    if (t == 0) {
        float ls = 0.f, ac = 0.f;
        #pragma unroll
        for (int r = 0; r < TM; ++r) { ls += srow[r][0]; ac += srow[r][1]; }
        partials[blk*2+0] = ls; partials[blk*2+1] = ac;
    }
}

extern "C" void kernel_launch(void* const* d_in, const int* in_sizes, int n_in,
                              void* d_out, int out_size, void* d_ws, size_t ws_size,
                              hipStream_t stream)
{
    const void *img = nullptr, *txt = nullptr, *w1 = nullptr, *w2 = nullptr;
    const void *b1 = nullptr, *b2 = nullptr, *tgt = nullptr;
    for (int i = 0; i < n_in; ++i) {
        long s = in_sizes[i];
        if      (s == (long)BSZ * DD) img = d_in[i];
        else if (s == (long)DD * NN)  txt = d_in[i];
        else if (s == (long)DD * HH) { if (!w1) w1 = d_in[i]; else w2 = d_in[i]; }
        else if (s == HH)  b1 = d_in[i];
        else if (s == DD)  b2 = d_in[i];
        else if (s == BSZ) tgt = d_in[i];
    }
    if (!img || !txt || !w1 || !w2 || !b1 || !b2 || !tgt) {
        img = d_in[0]; txt = d_in[1]; w1 = d_in[2]; b1 = d_in[3];
        w2 = d_in[4]; b2 = d_in[5]; tgt = d_in[8];
    }

    const size_t nTxt = (size_t)1024 * 512, nW = (size_t)128 * 512;
    const size_t needBytes = (2 * nTxt + 4 * nW) * 2 + 16384 + 256;

    if (ws_size >= needBytes) {
        unsigned short* txtTh = (unsigned short*)d_ws;
        unsigned short* txtTl = txtTh + nTxt;
        unsigned short* w1Th  = txtTl + nTxt;
        unsigned short* w1Tl  = w1Th + nW;
        unsigned short* w2Th  = w1Tl + nW;
        unsigned short* w2Tl  = w2Th + nW;
        float* partials = (float*)(w2Tl + nW);

        cv16_prep_txt<<<1024, 256, 0, stream>>>((const float*)txt, txtTh, txtTl);
        cv16_prep_w1<<<128, 256, 0, stream>>>((const float*)w1, w1Th, w1Tl);
        cv16_prep_w2<<<512, 128, 0, stream>>>((const float*)w2, w2Th, w2Tl);
        cv16_main<<<NBLK, 512, 0, stream>>>((const float*)img, (const float*)b1,
                                            (const float*)b2, txtTh, txtTl,
                                            w1Th, w1Tl, w2Th, w2Tl,
                                            (const unsigned*)tgt, partials);
        cv16_final<<<1, 256, 0, stream>>>(partials, (float*)d_out);
    } else {
        float* partials = (float*)d_ws;
        cv16_fb_main<<<NBLK, 256, 0, stream>>>((const float*)img, (const float*)txt,
                                               (const float*)w1, (const float*)b1,
                                               (const float*)w2, (const float*)b2,
                                               (const unsigned*)tgt, partials);
        cv16_final<<<1, 256, 0, stream>>>(partials, (float*)d_out);
    }
}